// Round 8
// baseline (149.423 us; speedup 1.0000x reference)
//
#include <hip/hip_runtime.h>

#define IN_F     512
#define OUT_F    10240
#define NPROJ    6
#define THREADS  512
#define PER_T    (OUT_F / THREADS)   // 20 outputs per thread
#define ROWS     4                   // batch rows per group
#define GRP      2                   // groups per block (pipelined)
#define NBINS    256
#define CAND_CAP 128
#define NWAVES   (THREADS / 64)
#define FLT_BIG  3.402823466e+38f

typedef float    float4v __attribute__((ext_vector_type(4)));
typedef unsigned uint4v  __attribute__((ext_vector_type(4)));

// One block = 2 pipelined groups of 4 batch rows.
// Per group: transposed-tile gather (ds_read_b128 serves 4 rows) ->
// thread-max histogram select (round-7, exact) -> fire-and-forget stores.
// Group g+1's tile is prefetched to registers during group g (issue-early),
// ds_written after select (write-late); stores of g drain under g+1's gather.
__global__ __launch_bounds__(THREADS, 4) void flyhash_wta_kernel(
    const float* __restrict__ inp,
    const int*   __restrict__ proj,
    const int*   __restrict__ hlen,
    float*       __restrict__ out,
    int batch)
{
    __shared__ float4v  s_rowT[GRP][IN_F];        // 2 x 8 KB double buffer
    __shared__ unsigned s_hist[ROWS][NBINS];      // 4 KB thread-max histogram
    __shared__ float4v  s_red[NWAVES];            // reduce scratch
    __shared__ unsigned s_bin[ROWS];
    __shared__ float    s_cand[ROWS][CAND_CAP];   // 2 KB
    __shared__ unsigned s_cnt[ROWS];
    __shared__ float    s_kth[ROWS];
    __shared__ int      s_pc[ROWS][NWAVES];       // bisection partial counts

    const int t    = threadIdx.x;
    const int lane = t & 63;
    const int wave = t >> 6;
    const int rr   = t & 3;          // staging: row within group
    const int cb   = t >> 2;         // staging: base feature column
    const int bg0  = blockIdx.x * GRP;

    // --- prologue: stage group 0 into buffer 0 (transposed, linear writes) ---
    {
        int br = bg0 * ROWS + rr;
        if (br >= batch) br = batch - 1;           // clamp (reads only)
        const float* g = inp + (size_t)br * IN_F;
        float stg0[4];
#pragma unroll
        for (int p = 0; p < 4; ++p) stg0[p] = g[cb + p * (THREADS / 4)];
#pragma unroll
        for (int p = 0; p < 4; ++p)
            ((float*)&s_rowT[0][0])[(cb + p * (THREADS / 4)) * 4 + rr] = stg0[p];
    }

    const int k0 = hlen[0];

#pragma unroll 1
    for (int g = 0; g < GRP; ++g) {
        const int b0 = (bg0 + g) * ROWS;
        const float4v* rowT = &s_rowT[g & 1][0];

        // --- prefetch next group's tile into registers (issue-early) ---
        float stg[4];
        const bool pf = (g + 1 < GRP);
        if (pf) {
            int br = (bg0 + g + 1) * ROWS + rr;
            if (br >= batch) br = batch - 1;
            const float* gp = inp + (size_t)br * IN_F;
#pragma unroll
            for (int p = 0; p < 4; ++p) stg[p] = gp[cb + p * (THREADS / 4)];
        }

        // --- gather: one ds_read_b128 per index serves all 4 rows ---
        float4v acc[PER_T];
#pragma unroll
        for (int i = 0; i < PER_T; ++i) {
            const int o = t + i * THREADS;
            const int2* ip = (const int2*)(proj + (size_t)o * NPROJ);
            const int2 p0 = ip[0];
            const int2 p1 = ip[1];
            const int2 p2 = ip[2];
            // same per-component summation order as rounds 1-7 (absmax 0)
            const float4v a01 = rowT[p0.x] + rowT[p0.y];
            const float4v a23 = rowT[p1.x] + rowT[p1.y];
            const float4v a45 = rowT[p2.x] + rowT[p2.y];
            acc[i] = (a01 + a23) + a45;
        }

        // --- per-thread per-row max ---
        float4v tmax = acc[0];
#pragma unroll
        for (int i = 1; i < PER_T; ++i) {
            tmax.x = fmaxf(tmax.x, acc[i].x);
            tmax.y = fmaxf(tmax.y, acc[i].y);
            tmax.z = fmaxf(tmax.z, acc[i].z);
            tmax.w = fmaxf(tmax.w, acc[i].w);
        }

        // --- block max M4 (write scratch, zero select state, one barrier) ---
        float4v m4 = tmax;
#pragma unroll
        for (int d = 1; d < 64; d <<= 1) {
            m4.x = fmaxf(m4.x, __shfl_xor(m4.x, d));
            m4.y = fmaxf(m4.y, __shfl_xor(m4.y, d));
            m4.z = fmaxf(m4.z, __shfl_xor(m4.z, d));
            m4.w = fmaxf(m4.w, __shfl_xor(m4.w, d));
        }
        if (lane == 0) s_red[wave] = m4;
        ((unsigned*)s_hist)[t]           = 0u;
        ((unsigned*)s_hist)[t + THREADS] = 0u;
        if (t < ROWS) { s_cnt[t] = 0u; s_kth[t] = 0.0f; }
        __syncthreads();
        float4v M4 = s_red[0];
#pragma unroll
        for (int w = 1; w < NWAVES; ++w) {
            M4.x = fmaxf(M4.x, s_red[w].x);
            M4.y = fmaxf(M4.y, s_red[w].y);
            M4.z = fmaxf(M4.z, s_red[w].z);
            M4.w = fmaxf(M4.w, s_red[w].w);
        }

        // --- histogram of thread-maxes: 4 atomics/thread ---
        unsigned rowvalid = 0;
        int bin_[ROWS];
#pragma unroll
        for (int r = 0; r < ROWS; ++r) {
            const float Mr = M4[r];
            const float scl = (Mr > 0.0f) ? 255.0f / Mr : 0.0f;
            int b = (int)(tmax[r] * scl);
            b = b < 0 ? 0 : (b > NBINS - 1 ? NBINS - 1 : b);
            bin_[r] = b;
            if (Mr > 0.0f) {
                rowvalid |= (1u << r);
                atomicAdd(&s_hist[r][b], 1u);
            }
        }
        __syncthreads();

        // --- suffix scan on max-histogram: wave r -> row r ---
        if (wave < ROWS && (rowvalid & (1u << wave))) {
            const uint4v h = ((const uint4v*)&s_hist[wave][0])[lane];
            const unsigned s3 = h.w;
            const unsigned s2 = h.z + s3;
            const unsigned s1 = h.y + s2;
            const unsigned s0 = h.x + s1;
            unsigned T = s0;
#pragma unroll
            for (int d = 1; d < 64; d <<= 1) {
                const unsigned o = __shfl_down(T, d);
                if (lane + d < 64) T += o;
            }
            const unsigned A = T - s0;             // sum over lanes > lane
            const unsigned S0 = A + s0, S1 = A + s1, S2 = A + s2, S3 = A + s3;
            if (h.x && (int)S0 >= k0 && (int)(S0 - h.x) < k0) s_bin[wave] = 4u * lane + 0u;
            if (h.y && (int)S1 >= k0 && (int)(S1 - h.y) < k0) s_bin[wave] = 4u * lane + 1u;
            if (h.z && (int)S2 >= k0 && (int)(S2 - h.z) < k0) s_bin[wave] = 4u * lane + 2u;
            if (h.w && (int)S3 >= k0 && (int)(S3 - h.w) < k0) s_bin[wave] = 4u * lane + 3u;
            if (lane == 0 && (int)(A + s0) < k0) s_bin[wave] = 0u;   // k > #maxes
        }
        __syncthreads();

        // --- T4 = min over qualifying thread-maxes (bin >= selected bin) ---
        float4v q4;
#pragma unroll
        for (int r = 0; r < ROWS; ++r)
            q4[r] = (((rowvalid >> r) & 1u) && bin_[r] >= (int)s_bin[r]) ? tmax[r] : FLT_BIG;
#pragma unroll
        for (int d = 1; d < 64; d <<= 1) {
            q4.x = fminf(q4.x, __shfl_xor(q4.x, d));
            q4.y = fminf(q4.y, __shfl_xor(q4.y, d));
            q4.z = fminf(q4.z, __shfl_xor(q4.z, d));
            q4.w = fminf(q4.w, __shfl_xor(q4.w, d));
        }
        if (lane == 0) s_red[wave] = q4;
        __syncthreads();
        float4v T4 = s_red[0];
#pragma unroll
        for (int w = 1; w < NWAVES; ++w) {
            T4.x = fminf(T4.x, s_red[w].x);
            T4.y = fminf(T4.y, s_red[w].y);
            T4.z = fminf(T4.z, s_red[w].z);
            T4.w = fminf(T4.w, s_red[w].w);
        }

        // --- collect candidates >= T (sparse atomics; original values) ---
#pragma unroll
        for (int i = 0; i < PER_T; ++i) {
#pragma unroll
            for (int r = 0; r < ROWS; ++r) {
                const float v = acc[i][r];
                if (v >= T4[r]) {
                    const unsigned idx = atomicAdd(&s_cnt[r], 1u);
                    if (idx < CAND_CAP) s_cand[r][idx] = v;
                }
            }
        }
        __syncthreads();

        // --- overflow fallback: exact uint bisection on count(>=x) (rare) ---
        unsigned ovf = 0;
#pragma unroll
        for (int r = 0; r < ROWS; ++r)
            if (((rowvalid >> r) & 1u) && s_cnt[r] > CAND_CAP) ovf |= (1u << r);

        if (ovf) {
            unsigned lo[ROWS], hi[ROWS];
#pragma unroll
            for (int r = 0; r < ROWS; ++r) {
                lo[r] = __float_as_uint(T4[r]);        // count(>=lo) >= k
                hi[r] = __float_as_uint(M4[r]) + 1u;   // count(>=hi) == 0 < k
            }
            for (int it = 0; it < 34; ++it) {
                unsigned work = 0;
#pragma unroll
                for (int r = 0; r < ROWS; ++r)
                    if (((ovf >> r) & 1u) && hi[r] - lo[r] > 1u) work |= (1u << r);
                if (!work) break;
                unsigned mid[ROWS];
#pragma unroll
                for (int r = 0; r < ROWS; ++r) mid[r] = lo[r] + (hi[r] - lo[r]) / 2u;
                int c0 = 0, c1 = 0, c2 = 0, c3 = 0;
#pragma unroll
                for (int i = 0; i < PER_T; ++i) {
                    c0 += (__float_as_uint(acc[i].x) >= mid[0]);
                    c1 += (__float_as_uint(acc[i].y) >= mid[1]);
                    c2 += (__float_as_uint(acc[i].z) >= mid[2]);
                    c3 += (__float_as_uint(acc[i].w) >= mid[3]);
                }
#pragma unroll
                for (int d = 1; d < 64; d <<= 1) {
                    c0 += __shfl_xor(c0, d);
                    c1 += __shfl_xor(c1, d);
                    c2 += __shfl_xor(c2, d);
                    c3 += __shfl_xor(c3, d);
                }
                if (lane == 0) {
                    s_pc[0][wave] = c0; s_pc[1][wave] = c1;
                    s_pc[2][wave] = c2; s_pc[3][wave] = c3;
                }
                __syncthreads();
#pragma unroll
                for (int r = 0; r < ROWS; ++r) {
                    if ((work >> r) & 1u) {
                        int c = 0;
#pragma unroll
                        for (int w = 0; w < NWAVES; ++w) c += s_pc[r][w];
                        if (c >= k0) lo[r] = mid[r]; else hi[r] = mid[r];
                    }
                }
                __syncthreads();
            }
            if (t == 0) {
#pragma unroll
                for (int r = 0; r < ROWS; ++r)
                    if ((ovf >> r) & 1u) s_kth[r] = __uint_as_float(lo[r]);
            }
        }

        // --- exact rank select over candidates: wave r -> row r ---
        if (wave < ROWS && (rowvalid & (1u << wave)) && !((ovf >> wave) & 1u)) {
            const unsigned c = s_cnt[wave];
            for (unsigned s = lane; s < c; s += 64) {
                const float v = s_cand[wave][s];
                int gt = 0, eq = 0;
                for (unsigned j = 0; j < c; ++j) {
                    const float u = s_cand[wave][j];
                    gt += (u > v);
                    eq += (u == v);
                }
                if (gt < k0 && gt + eq >= k0) s_kth[wave] = v;  // ties write same value
            }
        }
        __syncthreads();
        const float4v kth4 = { s_kth[0], s_kth[1], s_kth[2], s_kth[3] };

        // --- restage next tile (write-late), barrier, THEN issue stores ---
        if (pf) {
#pragma unroll
            for (int p = 0; p < 4; ++p)
                ((float*)&s_rowT[(g + 1) & 1][0])[(cb + p * (THREADS / 4)) * 4 + rr] = stg[p];
        }
        __syncthreads();   // buf ready; everyone has read s_kth

        // --- fire-and-forget predicated coalesced stores (round-4 layout);
        //     next iteration's gather has no barrier before its ds_reads ---
#pragma unroll
        for (int r = 0; r < ROWS; ++r) {
            const int br = b0 + r;
            if (br < batch) {
                float* orow = out + (size_t)br * OUT_F;
#pragma unroll
                for (int i = 0; i < PER_T; ++i) {
                    const float v = acc[i][r];
                    orow[t + i * THREADS] = (v >= kth4[r]) ? v : 0.0f;
                }
            }
        }
    }
}

extern "C" void kernel_launch(void* const* d_in, const int* in_sizes, int n_in,
                              void* d_out, int out_size, void* d_ws, size_t ws_size,
                              hipStream_t stream) {
    const float* inp  = (const float*)d_in[0];
    const int*   proj = (const int*)d_in[1];
    const int*   hlen = (const int*)d_in[2];
    float*       out  = (float*)d_out;

    const int batch  = in_sizes[0] / IN_F;                    // 4096
    const int blocks = (batch + ROWS * GRP - 1) / (ROWS * GRP);  // 512

    hipLaunchKernelGGL(flyhash_wta_kernel, dim3(blocks), dim3(THREADS), 0, stream,
                       inp, proj, hlen, out, batch);
}

// Round 9
// 62.953 us; speedup vs baseline: 2.3736x; 2.3736x over previous
//
#include <hip/hip_runtime.h>

#define IN_F     512
#define OUT_F    10240
#define NPROJ    6
#define THREADS  512
#define PER_T    (OUT_F / THREADS)   // 20 outputs per thread
#define ROWS     4                   // batch rows per block
#define NBINS    256
#define CAND_CAP 128
#define NWAVES   (THREADS / 64)
#define NSLOTS   (NWAVES * PER_T * NPROJ)   // 960 wave-read slots
#define FLT_BIG  3.402823466e+38f

typedef float    float4v __attribute__((ext_vector_type(4)));
typedef unsigned uint4v  __attribute__((ext_vector_type(4)));

// ---------------------------------------------------------------------------
// Two-choice bank balancing. proj is identical for all blocks/replays, so we
// precompute, for each wave-read slot (wave w, output i, index j), which copy
// each lane should read: copy A at granule f (quad f&7) or copy B at granule
// 512 + pi(f) (quad (f>>3)&7), greedily minimizing the max per-quad load.
// Output: proj2 = granule table, same shape/order as proj.
// ---------------------------------------------------------------------------
__global__ void balance_kernel(const int* __restrict__ proj,
                               int* __restrict__ proj2)
{
    const int s = blockIdx.x * 64 + threadIdx.x;
    if (s >= NSLOTS) return;
    const int j = s % NPROJ;
    const int i = (s / NPROJ) % PER_T;
    const int w = s / (NPROJ * PER_T);

    unsigned long long cnt = 0ull;              // 8 quads x 8-bit counters
    for (int l = 0; l < 64; ++l) {
        const int o   = (w * 64 + l) + i * THREADS;
        const int idx = o * NPROJ + j;
        const int f   = proj[idx];
        const int qa  = f & 7;
        const int qb  = (f >> 3) & 7;
        const unsigned ca = (unsigned)(cnt >> (qa * 8)) & 255u;
        const unsigned cb = (unsigned)(cnt >> (qb * 8)) & 255u;
        const bool useB = cb < ca;
        const int q = useB ? qb : qa;
        cnt += 1ull << (q * 8);
        proj2[idx] = useB ? (512 + ((f >> 3) | ((f & 7) << 6))) : f;
    }
}

// ---------------------------------------------------------------------------
// Main kernel: round-7 structure (best clean baseline, 56 µs) with a
// replicated two-choice tile. Gather reads granules 0..1023 from proj2.
// Selection: thread-max histogram -> suffix scan -> T bound -> exact rank
// select (bit-exact vs reference, ties included). absmax must stay 0.
// ---------------------------------------------------------------------------
__global__ __launch_bounds__(THREADS, 4) void flyhash_wta_kernel(
    const float* __restrict__ inp,
    const int*   __restrict__ proj2,
    const int*   __restrict__ hlen,
    float*       __restrict__ out,
    int batch)
{
    __shared__ float4v  s_rowT[1024];             // 16 KB: copy A [0,512) + copy B [512,1024)
    __shared__ unsigned s_hist[ROWS][NBINS];      // 4 KB thread-max histogram
    __shared__ float4v  s_red[NWAVES];            // reduce scratch
    __shared__ unsigned s_bin[ROWS];
    __shared__ float    s_cand[ROWS][CAND_CAP];   // 2 KB
    __shared__ unsigned s_cnt[ROWS];
    __shared__ float    s_kth[ROWS];
    __shared__ int      s_pc[ROWS][NWAVES];       // bisection partial counts

    const int t    = threadIdx.x;
    const int lane = t & 63;
    const int wave = t >> 6;
    const int b0   = blockIdx.x * ROWS;

    // --- stage copy A: 4 rows transposed (linear LDS writes); zero state ---
    {
        const int r  = t & 3;
        const int cb = t >> 2;
        int br = b0 + r;
        if (br >= batch) br = batch - 1;           // clamp (reads only)
        const float* g = inp + (size_t)br * IN_F;
#pragma unroll
        for (int p = 0; p < 4; ++p) {
            const int c = cb + p * (THREADS / 4);
            ((float*)s_rowT)[c * 4 + r] = g[c];
        }
    }
    if (t < ROWS) { s_cnt[t] = 0u; s_kth[t] = 0.0f; }
    ((unsigned*)s_hist)[t]           = 0u;
    ((unsigned*)s_hist)[t + THREADS] = 0u;
    __syncthreads();

    // --- build copy B: balanced b128 read (quad (t>>3)&7) ->
    //     write at 512 + pi(a) (quad t&7). Bitwise-identical values. ---
    {
        const int a  = (t & ~63) | ((t & 7) << 3) | ((t >> 3) & 7);  // bijective
        const float4v v = s_rowT[a];
        const int pa = (a >> 3) | ((a & 7) << 6);                    // 9-bit rot
        s_rowT[512 + pa] = v;
    }
    __syncthreads();

    const int k0 = hlen[0];

    // --- gather: one ds_read_b128 per granule serves all 4 rows ---
    float4v acc[PER_T];
#pragma unroll
    for (int i = 0; i < PER_T; ++i) {
        const int o = t + i * THREADS;
        const int2* ip = (const int2*)(proj2 + (size_t)o * NPROJ);
        const int2 p0 = ip[0];
        const int2 p1 = ip[1];
        const int2 p2 = ip[2];
        // same per-component summation order as rounds 1-8 (absmax 0)
        const float4v a01 = s_rowT[p0.x] + s_rowT[p0.y];
        const float4v a23 = s_rowT[p1.x] + s_rowT[p1.y];
        const float4v a45 = s_rowT[p2.x] + s_rowT[p2.y];
        acc[i] = (a01 + a23) + a45;
    }

    // --- per-thread per-row max ---
    float4v tmax = acc[0];
#pragma unroll
    for (int i = 1; i < PER_T; ++i) {
        tmax.x = fmaxf(tmax.x, acc[i].x);
        tmax.y = fmaxf(tmax.y, acc[i].y);
        tmax.z = fmaxf(tmax.z, acc[i].z);
        tmax.w = fmaxf(tmax.w, acc[i].w);
    }

    // --- block max M4 ---
    float4v m4 = tmax;
#pragma unroll
    for (int d = 1; d < 64; d <<= 1) {
        m4.x = fmaxf(m4.x, __shfl_xor(m4.x, d));
        m4.y = fmaxf(m4.y, __shfl_xor(m4.y, d));
        m4.z = fmaxf(m4.z, __shfl_xor(m4.z, d));
        m4.w = fmaxf(m4.w, __shfl_xor(m4.w, d));
    }
    if (lane == 0) s_red[wave] = m4;
    __syncthreads();
    float4v M4 = s_red[0];
#pragma unroll
    for (int w = 1; w < NWAVES; ++w) {
        M4.x = fmaxf(M4.x, s_red[w].x);
        M4.y = fmaxf(M4.y, s_red[w].y);
        M4.z = fmaxf(M4.z, s_red[w].z);
        M4.w = fmaxf(M4.w, s_red[w].w);
    }

    // --- histogram of thread-maxes: 4 atomics/thread total ---
    unsigned rowvalid = 0;
    int bin_[ROWS];
#pragma unroll
    for (int r = 0; r < ROWS; ++r) {
        const float Mr = M4[r];
        const float scl = (Mr > 0.0f) ? 255.0f / Mr : 0.0f;
        int b = (int)(tmax[r] * scl);
        b = b < 0 ? 0 : (b > NBINS - 1 ? NBINS - 1 : b);
        bin_[r] = b;
        if (Mr > 0.0f) {
            rowvalid |= (1u << r);
            atomicAdd(&s_hist[r][b], 1u);
        }
    }
    __syncthreads();

    // --- suffix scan on max-histogram: wave r -> row r ---
    if (wave < ROWS && (rowvalid & (1u << wave))) {
        const uint4v h = ((const uint4v*)&s_hist[wave][0])[lane];
        const unsigned s3 = h.w;
        const unsigned s2 = h.z + s3;
        const unsigned s1 = h.y + s2;
        const unsigned s0 = h.x + s1;
        unsigned T = s0;
#pragma unroll
        for (int d = 1; d < 64; d <<= 1) {
            const unsigned o = __shfl_down(T, d);
            if (lane + d < 64) T += o;
        }
        const unsigned A = T - s0;                 // sum over lanes > lane
        const unsigned S0 = A + s0, S1 = A + s1, S2 = A + s2, S3 = A + s3;
        if (h.x && (int)S0 >= k0 && (int)(S0 - h.x) < k0) s_bin[wave] = 4u * lane + 0u;
        if (h.y && (int)S1 >= k0 && (int)(S1 - h.y) < k0) s_bin[wave] = 4u * lane + 1u;
        if (h.z && (int)S2 >= k0 && (int)(S2 - h.z) < k0) s_bin[wave] = 4u * lane + 2u;
        if (h.w && (int)S3 >= k0 && (int)(S3 - h.w) < k0) s_bin[wave] = 4u * lane + 3u;
        if (lane == 0 && (int)(A + s0) < k0) s_bin[wave] = 0u;   // k > #maxes
    }
    __syncthreads();

    // --- T4 = min over qualifying thread-maxes (bin >= selected bin) ---
    float4v q4;
#pragma unroll
    for (int r = 0; r < ROWS; ++r)
        q4[r] = (((rowvalid >> r) & 1u) && bin_[r] >= (int)s_bin[r]) ? tmax[r] : FLT_BIG;
#pragma unroll
    for (int d = 1; d < 64; d <<= 1) {
        q4.x = fminf(q4.x, __shfl_xor(q4.x, d));
        q4.y = fminf(q4.y, __shfl_xor(q4.y, d));
        q4.z = fminf(q4.z, __shfl_xor(q4.z, d));
        q4.w = fminf(q4.w, __shfl_xor(q4.w, d));
    }
    if (lane == 0) s_red[wave] = q4;
    __syncthreads();
    float4v T4 = s_red[0];
#pragma unroll
    for (int w = 1; w < NWAVES; ++w) {
        T4.x = fminf(T4.x, s_red[w].x);
        T4.y = fminf(T4.y, s_red[w].y);
        T4.z = fminf(T4.z, s_red[w].z);
        T4.w = fminf(T4.w, s_red[w].w);
    }

    // --- collect candidates >= T (sparse atomics; exact original values) ---
#pragma unroll
    for (int i = 0; i < PER_T; ++i) {
#pragma unroll
        for (int r = 0; r < ROWS; ++r) {
            const float v = acc[i][r];
            if (v >= T4[r]) {
                const unsigned idx = atomicAdd(&s_cnt[r], 1u);
                if (idx < CAND_CAP) s_cand[r][idx] = v;
            }
        }
    }
    __syncthreads();

    // --- overflow fallback: exact uint bisection on count(>=x) (rare) ---
    unsigned ovf = 0;
#pragma unroll
    for (int r = 0; r < ROWS; ++r)
        if (((rowvalid >> r) & 1u) && s_cnt[r] > CAND_CAP) ovf |= (1u << r);

    if (ovf) {
        unsigned lo[ROWS], hi[ROWS];
#pragma unroll
        for (int r = 0; r < ROWS; ++r) {
            lo[r] = __float_as_uint(T4[r]);        // count(>=lo) >= k
            hi[r] = __float_as_uint(M4[r]) + 1u;   // count(>=hi) == 0 < k
        }
        for (int it = 0; it < 34; ++it) {
            unsigned work = 0;
#pragma unroll
            for (int r = 0; r < ROWS; ++r)
                if (((ovf >> r) & 1u) && hi[r] - lo[r] > 1u) work |= (1u << r);
            if (!work) break;
            unsigned mid[ROWS];
#pragma unroll
            for (int r = 0; r < ROWS; ++r) mid[r] = lo[r] + (hi[r] - lo[r]) / 2u;
            int c0 = 0, c1 = 0, c2 = 0, c3 = 0;
#pragma unroll
            for (int i = 0; i < PER_T; ++i) {
                c0 += (__float_as_uint(acc[i].x) >= mid[0]);
                c1 += (__float_as_uint(acc[i].y) >= mid[1]);
                c2 += (__float_as_uint(acc[i].z) >= mid[2]);
                c3 += (__float_as_uint(acc[i].w) >= mid[3]);
            }
#pragma unroll
            for (int d = 1; d < 64; d <<= 1) {
                c0 += __shfl_xor(c0, d);
                c1 += __shfl_xor(c1, d);
                c2 += __shfl_xor(c2, d);
                c3 += __shfl_xor(c3, d);
            }
            if (lane == 0) {
                s_pc[0][wave] = c0; s_pc[1][wave] = c1;
                s_pc[2][wave] = c2; s_pc[3][wave] = c3;
            }
            __syncthreads();
#pragma unroll
            for (int r = 0; r < ROWS; ++r) {
                if ((work >> r) & 1u) {
                    int c = 0;
#pragma unroll
                    for (int w = 0; w < NWAVES; ++w) c += s_pc[r][w];
                    if (c >= k0) lo[r] = mid[r]; else hi[r] = mid[r];
                }
            }
            __syncthreads();
        }
        if (t == 0) {
#pragma unroll
            for (int r = 0; r < ROWS; ++r)
                if ((ovf >> r) & 1u) s_kth[r] = __uint_as_float(lo[r]);
        }
    }

    // --- exact rank select over candidates: wave r -> row r ---
    if (wave < ROWS && (rowvalid & (1u << wave)) && !((ovf >> wave) & 1u)) {
        const unsigned c = s_cnt[wave];
        for (unsigned s = lane; s < c; s += 64) {
            const float v = s_cand[wave][s];
            int gt = 0, eq = 0;
            for (unsigned j = 0; j < c; ++j) {
                const float u = s_cand[wave][j];
                gt += (u > v);
                eq += (u == v);
            }
            if (gt < k0 && gt + eq >= k0) s_kth[wave] = v;   // ties write same value
        }
    }
    __syncthreads();
    const float4v kth4 = { s_kth[0], s_kth[1], s_kth[2], s_kth[3] };

    // --- predicated coalesced stores (round-4 layout) ---
#pragma unroll
    for (int r = 0; r < ROWS; ++r) {
        const int br = b0 + r;
        if (br < batch) {
            float* orow = out + (size_t)br * OUT_F;
#pragma unroll
            for (int i = 0; i < PER_T; ++i) {
                const float v = acc[i][r];
                orow[t + i * THREADS] = (v >= kth4[r]) ? v : 0.0f;
            }
        }
    }
}

extern "C" void kernel_launch(void* const* d_in, const int* in_sizes, int n_in,
                              void* d_out, int out_size, void* d_ws, size_t ws_size,
                              hipStream_t stream) {
    const float* inp  = (const float*)d_in[0];
    const int*   proj = (const int*)d_in[1];
    const int*   hlen = (const int*)d_in[2];
    float*       out  = (float*)d_out;

    const int batch  = in_sizes[0] / IN_F;            // 4096
    const int blocks = (batch + ROWS - 1) / ROWS;     // 1024

    const size_t proj2_bytes = (size_t)OUT_F * NPROJ * sizeof(int);  // 245,760 B
    const bool balanced = (ws_size >= proj2_bytes);
    int* proj2 = (int*)d_ws;

    if (balanced) {
        hipLaunchKernelGGL(balance_kernel, dim3((NSLOTS + 63) / 64), dim3(64),
                           0, stream, proj, proj2);
    }
    // Fallback: original proj entries are valid copy-A granules (0..511).
    hipLaunchKernelGGL(flyhash_wta_kernel, dim3(blocks), dim3(THREADS), 0, stream,
                       inp, balanced ? (const int*)proj2 : proj, hlen, out, batch);
}

// Round 10
// 52.826 us; speedup vs baseline: 2.8286x; 1.1917x over previous
//
#include <hip/hip_runtime.h>

#define IN_F     512
#define OUT_F    10240
#define NPROJ    6
#define THREADS  512
#define PER_T    (OUT_F / THREADS)   // 20 outputs per thread
#define ROWS     4                   // batch rows per block
#define NBINS    256
#define CAND_CAP 128
#define NWAVES   (THREADS / 64)
#define BIN_OFF  8064u               // (bits>>17) of 0.5f; bins cover [0.5, 8)

typedef float    float4v __attribute__((ext_vector_type(4)));
typedef unsigned uint4v  __attribute__((ext_vector_type(4)));

// One block = 4 batch rows (round-7 structure, static-bit-bin selection).
// bin(v) = clamp((float_bits(v) >> 17) - 8064, 0, 255): monotone for v >= 0,
// bin edges are exact float thresholds -> no block-max reduce, no T-min
// reduce, no data-dependent scaling. Selection: per-thread max -> 512-max
// static histogram (4 atomics/thread) -> suffix scan -> T = lower edge of
// the bin holding the k-th largest thread-max (provably <= kth value) ->
// collect candidates >= T -> exact rank select on original values.
// Fallback (bin-0 rows / overflow): exact uint bisection on count(>=x).
__global__ __launch_bounds__(THREADS, 4) void flyhash_wta_kernel(
    const float* __restrict__ inp,
    const int*   __restrict__ proj,
    const int*   __restrict__ hlen,
    float*       __restrict__ out,
    int batch)
{
    __shared__ float4v  s_rowT[IN_F];             // 8 KB transposed tile
    __shared__ unsigned s_hist[ROWS][NBINS];      // 4 KB thread-max histogram
    __shared__ unsigned s_bin[ROWS];
    __shared__ float    s_cand[ROWS][CAND_CAP];   // 2 KB
    __shared__ unsigned s_cnt[ROWS];
    __shared__ float    s_kth[ROWS];
    __shared__ int      s_pc[ROWS][NWAVES];       // bisection partial counts

    const int t    = threadIdx.x;
    const int lane = t & 63;
    const int wave = t >> 6;
    const int b0   = blockIdx.x * ROWS;

    // --- stage 4 rows transposed (linear LDS writes); zero select state ---
    {
        const int r  = t & 3;
        const int cb = t >> 2;
        int br = b0 + r;
        if (br >= batch) br = batch - 1;           // clamp (reads only)
        const float* g = inp + (size_t)br * IN_F;
#pragma unroll
        for (int p = 0; p < 4; ++p) {
            const int c = cb + p * (THREADS / 4);
            ((float*)s_rowT)[c * 4 + r] = g[c];
        }
    }
    ((unsigned*)s_hist)[t]           = 0u;
    ((unsigned*)s_hist)[t + THREADS] = 0u;
    if (t < ROWS) { s_cnt[t] = 0u; s_kth[t] = 0.0f; }
    __syncthreads();

    const int k0 = hlen[0];

    // --- gather: one ds_read_b128 per index serves all 4 rows (round-4) ---
    float4v acc[PER_T];
#pragma unroll
    for (int i = 0; i < PER_T; ++i) {
        const int o = t + i * THREADS;
        const int2* ip = (const int2*)(proj + (size_t)o * NPROJ);
        const int2 p0 = ip[0];
        const int2 p1 = ip[1];
        const int2 p2 = ip[2];
        // same per-component summation order as rounds 1-9 (absmax 0)
        const float4v a01 = s_rowT[p0.x] + s_rowT[p0.y];
        const float4v a23 = s_rowT[p1.x] + s_rowT[p1.y];
        const float4v a45 = s_rowT[p2.x] + s_rowT[p2.y];
        acc[i] = (a01 + a23) + a45;
    }

    // --- per-thread per-row max ---
    float4v tmax = acc[0];
#pragma unroll
    for (int i = 1; i < PER_T; ++i) {
        tmax.x = fmaxf(tmax.x, acc[i].x);
        tmax.y = fmaxf(tmax.y, acc[i].y);
        tmax.z = fmaxf(tmax.z, acc[i].z);
        tmax.w = fmaxf(tmax.w, acc[i].w);
    }

    // --- static-bit histogram of thread-maxes: 4 atomics/thread, no reduce ---
#pragma unroll
    for (int r = 0; r < ROWS; ++r) {
        int key = (int)(__float_as_uint(tmax[r]) >> 17) - (int)BIN_OFF;
        key = key < 0 ? 0 : (key > NBINS - 1 ? NBINS - 1 : key);
        atomicAdd(&s_hist[r][key], 1u);
    }
    __syncthreads();

    // --- suffix scan on max-histogram: wave r -> row r (lane holds 4 bins) ---
    if (wave < ROWS) {
        const uint4v h = ((const uint4v*)&s_hist[wave][0])[lane];
        const unsigned s3 = h.w;
        const unsigned s2 = h.z + s3;
        const unsigned s1 = h.y + s2;
        const unsigned s0 = h.x + s1;
        unsigned T = s0;
#pragma unroll
        for (int d = 1; d < 64; d <<= 1) {
            const unsigned o = __shfl_down(T, d);
            if (lane + d < 64) T += o;
        }
        const unsigned A = T - s0;                 // sum over lanes > lane
        const unsigned S0 = A + s0, S1 = A + s1, S2 = A + s2, S3 = A + s3;
        if (h.x && (int)S0 >= k0 && (int)(S0 - h.x) < k0) s_bin[wave] = 4u * lane + 0u;
        if (h.y && (int)S1 >= k0 && (int)(S1 - h.y) < k0) s_bin[wave] = 4u * lane + 1u;
        if (h.z && (int)S2 >= k0 && (int)(S2 - h.z) < k0) s_bin[wave] = 4u * lane + 2u;
        if (h.w && (int)S3 >= k0 && (int)(S3 - h.w) < k0) s_bin[wave] = 4u * lane + 3u;
        if (lane == 0 && (int)(A + s0) < k0) s_bin[wave] = 0u;   // k > #maxes
    }
    __syncthreads();

    // --- T4[r] = exact lower edge of selected bin (<= kth value of row) ---
    float4v T4;
#pragma unroll
    for (int r = 0; r < ROWS; ++r) {
        const unsigned B = s_bin[r];
        T4[r] = (B == 0u) ? 0.0f : __uint_as_float((B + BIN_OFF) << 17);
    }

    // --- collect candidates >= T (sparse atomics; exact original values) ---
#pragma unroll
    for (int i = 0; i < PER_T; ++i) {
#pragma unroll
        for (int r = 0; r < ROWS; ++r) {
            const float v = acc[i][r];
            if (v >= T4[r]) {
                const unsigned idx = atomicAdd(&s_cnt[r], 1u);
                if (idx < CAND_CAP) s_cand[r][idx] = v;
            }
        }
    }
    __syncthreads();

    // --- overflow fallback: exact uint bisection on count(>=x) ---
    unsigned ovf = 0;
#pragma unroll
    for (int r = 0; r < ROWS; ++r)
        if (s_cnt[r] > CAND_CAP) ovf |= (1u << r);

    if (ovf) {
        unsigned lo[ROWS], hi[ROWS];
#pragma unroll
        for (int r = 0; r < ROWS; ++r) {
            lo[r] = __float_as_uint(T4[r]);        // count(>=lo) >= k
            hi[r] = 0x41000000u;                   // 8.0f: count(>=hi)==0 (acts < 6)
        }
        for (int it = 0; it < 34; ++it) {
            unsigned work = 0;
#pragma unroll
            for (int r = 0; r < ROWS; ++r)
                if (((ovf >> r) & 1u) && hi[r] - lo[r] > 1u) work |= (1u << r);
            if (!work) break;
            unsigned mid[ROWS];
#pragma unroll
            for (int r = 0; r < ROWS; ++r) mid[r] = lo[r] + (hi[r] - lo[r]) / 2u;
            int c0 = 0, c1 = 0, c2 = 0, c3 = 0;
#pragma unroll
            for (int i = 0; i < PER_T; ++i) {
                c0 += (__float_as_uint(acc[i].x) >= mid[0]);
                c1 += (__float_as_uint(acc[i].y) >= mid[1]);
                c2 += (__float_as_uint(acc[i].z) >= mid[2]);
                c3 += (__float_as_uint(acc[i].w) >= mid[3]);
            }
#pragma unroll
            for (int d = 1; d < 64; d <<= 1) {
                c0 += __shfl_xor(c0, d);
                c1 += __shfl_xor(c1, d);
                c2 += __shfl_xor(c2, d);
                c3 += __shfl_xor(c3, d);
            }
            if (lane == 0) {
                s_pc[0][wave] = c0; s_pc[1][wave] = c1;
                s_pc[2][wave] = c2; s_pc[3][wave] = c3;
            }
            __syncthreads();
#pragma unroll
            for (int r = 0; r < ROWS; ++r) {
                if ((work >> r) & 1u) {
                    int c = 0;
#pragma unroll
                    for (int w = 0; w < NWAVES; ++w) c += s_pc[r][w];
                    if (c >= k0) lo[r] = mid[r]; else hi[r] = mid[r];
                }
            }
            __syncthreads();
        }
        if (t == 0) {
#pragma unroll
            for (int r = 0; r < ROWS; ++r)
                if ((ovf >> r) & 1u) s_kth[r] = __uint_as_float(lo[r]);
        }
    }

    // --- exact rank select over candidates: wave r -> row r ---
    if (wave < ROWS && !((ovf >> wave) & 1u)) {
        const unsigned c = s_cnt[wave];
        for (unsigned s = lane; s < c; s += 64) {
            const float v = s_cand[wave][s];
            int gt = 0, eq = 0;
            for (unsigned j = 0; j < c; ++j) {
                const float u = s_cand[wave][j];
                gt += (u > v);
                eq += (u == v);
            }
            if (gt < k0 && gt + eq >= k0) s_kth[wave] = v;   // ties write same value
        }
    }
    __syncthreads();
    const float4v kth4 = { s_kth[0], s_kth[1], s_kth[2], s_kth[3] };

    // --- predicated coalesced stores (round-4 layout) ---
#pragma unroll
    for (int r = 0; r < ROWS; ++r) {
        const int br = b0 + r;
        if (br < batch) {
            float* orow = out + (size_t)br * OUT_F;
#pragma unroll
            for (int i = 0; i < PER_T; ++i) {
                const float v = acc[i][r];
                orow[t + i * THREADS] = (v >= kth4[r]) ? v : 0.0f;
            }
        }
    }
}

extern "C" void kernel_launch(void* const* d_in, const int* in_sizes, int n_in,
                              void* d_out, int out_size, void* d_ws, size_t ws_size,
                              hipStream_t stream) {
    const float* inp  = (const float*)d_in[0];
    const int*   proj = (const int*)d_in[1];
    const int*   hlen = (const int*)d_in[2];
    float*       out  = (float*)d_out;

    const int batch  = in_sizes[0] / IN_F;            // 4096
    const int blocks = (batch + ROWS - 1) / ROWS;     // 1024

    hipLaunchKernelGGL(flyhash_wta_kernel, dim3(blocks), dim3(THREADS), 0, stream,
                       inp, proj, hlen, out, batch);
}